// Round 5
// baseline (136.673 us; speedup 1.0000x reference)
//
#include <hip/hip_runtime.h>
#include <math.h>

// GCDD fused, register-pipeline v2 (single-path masking + occupancy cap).
// out = u + div( phi(G)*ux, phi(G)*uy ); 3x3 Sobel cross-correlations with zero
// padding at EVERY conv stage (intermediates forced to 0 outside the domain).
//
// Only u lives in LDS. Each thread owns a 4-wide x 8-tall output strip and
// computes ux/uy -> P,Q -> divergence as a rolling row pipeline in registers:
//   u row jr (su)  ->  ux/uy row e=jr-2  ->  P,Q row m=e-2  ->  out row o=m-2.
// P,Q are never materialized: each P/Q row is immediately reduced to
//   dP[c] = P[c+2]-P[c],  eQ[c] = Q[c]+2Q[c+1]+Q[c+2]
// and out row o = u + (dP[o]+2dP[o+1]+dP[o+2]) + (eQ[o+2]-eQ[o]).
//
// R4 -> R5: the EDGE/no-EDGE dual-inlined pipeline blew VGPR to 220 and
// occupancy to 10%. Now ONE code path: boundary zeroing via always-on masks
// (col-validity bools computed once -> SGPR pairs; row-validity 1 cmp/row;
// apply = v_cndmask). __launch_bounds__(256,3) caps VGPR ~170 (3 waves/SIMD).
//
// Tile: 128 wide (32 strips) x 64 tall (8 bands x 8 rows), 256 threads.
// su[r][c]: gy = ty0 + r - 3 (r=0..69), gx = tx0 + c - 4 (c=0..135).

#define TW 128
#define TH 64
#define NT 256
#define SUH 70
#define SUW 136

struct Smem { float su[SUH][SUW]; };

__global__ __launch_bounds__(NT, 3) void gcdd_fused(
    const float* __restrict__ u, float* __restrict__ out, int H, int W)
{
    __shared__ Smem s;
    const int tid = threadIdx.x;
    const int tx0 = blockIdx.x * TW;
    const int ty0 = blockIdx.y * TH;
    const long chan = blockIdx.z;
    const float* __restrict__ uc = u + chan * (long)H * W;
    float* __restrict__ oc = out + chan * (long)H * W;

    const bool inr = (tx0 >= 4) && (tx0 + TW + 4 <= W)
                  && (ty0 >= 3) && (ty0 + TH + 3 <= H);

    // ---- Stage 1: u tile -> LDS. 70 rows x 34 float4-groups ----
    for (int i = tid; i < SUH * 34; i += NT) {
        const int r = i / 34, g = i - r * 34;
        const int gy = ty0 + r - 3;
        const int gxb = tx0 + g * 4 - 4;
        float4 v;
        if (inr) {
            v = *(const float4*)(uc + (long)gy * W + gxb);
        } else {
            float e[4];
            #pragma unroll
            for (int k = 0; k < 4; ++k) {
                const int gx = gxb + k;
                const bool in = ((unsigned)gy < (unsigned)H) & ((unsigned)gx < (unsigned)W);
                e[k] = in ? uc[(long)gy * W + gx] : 0.f;
            }
            v = make_float4(e[0], e[1], e[2], e[3]);
        }
        *(float4*)&s.su[r][g * 4] = v;
    }
    __syncthreads();

    // ---- Stage 2: register pipeline (single path, masked) ----
    const int strip = tid & 31;
    const int band  = tid >> 5;
    const int c0 = strip * 4;   // tile out col base
    const int r0 = band * 8;    // tile out row base
    const long obase = (long)(ty0 + r0) * W + (tx0 + c0);

    // Column-validity masks for ux/uy cols c=0..7 (gx = tx0+c0-2+c).
    // P col c (0..5) maps to inx[c+1]. Divergent bools live in SGPR pairs.
    bool inx[8];
    #pragma unroll
    for (int c = 0; c < 8; ++c) {
        const int gx = tx0 + c0 - 2 + c;
        inx[c] = (unsigned)gx < (unsigned)W;
    }

    float uw[3][12];
    float xw[3][8], yw[3][8];
    float dP[3][4], eQ[3][4];

    #pragma unroll
    for (int jr = 0; jr < 14; ++jr) {
        {   // u row jr: su row r0+jr, su cols c0..c0+11 (tile cols c0-4..c0+7)
            float* w = uw[jr % 3];
            *(float4*)&w[0] = *(const float4*)&s.su[r0 + jr][c0];
            *(float4*)&w[4] = *(const float4*)&s.su[r0 + jr][c0 + 4];
            *(float4*)&w[8] = *(const float4*)&s.su[r0 + jr][c0 + 8];
        }
        if (jr < 2) continue;
        const int e = jr - 2;   // ux/uy row: gy = ty0 + r0 - 2 + e
        {
            const float* t = uw[(jr - 2) % 3];
            const float* m = uw[(jr - 1) % 3];
            const float* b = uw[jr % 3];
            float* xr = xw[e % 3];
            float* yr = yw[e % 3];
            const int gy = ty0 + r0 - 2 + e;
            const bool iny = (unsigned)gy < (unsigned)H;
            #pragma unroll
            for (int c = 0; c < 8; ++c) {   // ux col: tile c0-2+c, uses uw[c+1..c+3]
                float A = t[c+1], B = t[c+2], C = t[c+3];
                float D = m[c+1],             E = m[c+3];
                float F = b[c+1], Gg = b[c+2], Hh = b[c+3];
                float x = (C - A) + 2.f*(E - D) + (Hh - F);       // SOBEL_X
                float y = (F + 2.f*Gg + Hh) - (A + 2.f*B + C);    // SOBEL_Y
                const bool in = iny & inx[c];
                xr[c] = in ? x : 0.f;
                yr[c] = in ? y : 0.f;
            }
        }
        if (e < 2) continue;
        const int mI = e - 2;   // P,Q row: gy = ty0 + r0 - 1 + mI
        {
            const float* xt = xw[(e - 2) % 3];
            const float* xm = xw[(e - 1) % 3];
            const float* xb = xw[e % 3];
            const float* yt = yw[(e - 2) % 3];
            const float* ym = yw[(e - 1) % 3];
            const float* yb = yw[e % 3];
            const int gy = ty0 + r0 - 1 + mI;
            const bool iny = (unsigned)gy < (unsigned)H;
            float P[6], Q[6];
            #pragma unroll
            for (int c = 0; c < 6; ++c) {   // P col: tile c0-1+c, uses xw[c..c+2]
                float xc = xm[c+1], yc = ym[c+1];
                float uxx = (xt[c+2]-xt[c]) + 2.f*(xm[c+2]-xm[c]) + (xb[c+2]-xb[c]);
                float uxy = (xb[c] + 2.f*xb[c+1] + xb[c+2])
                          - (xt[c] + 2.f*xt[c+1] + xt[c+2]);
                float uyy = (yb[c] + 2.f*yb[c+1] + yb[c+2])
                          - (yt[c] + 2.f*yt[c+1] + yt[c+2]);
                float den = 1.f + xc*xc + yc*yc;
                float Gv = (uxx*uyy - uxy*uxy)
                         * __builtin_amdgcn_rcpf(den*den + 1e-6f);
                float phi = __expf(-fabsf(Gv));
                const bool in = iny & inx[c + 1];
                P[c] = in ? phi * xc : 0.f;
                Q[c] = in ? phi * yc : 0.f;
            }
            float* dp = dP[mI % 3];
            float* eq = eQ[mI % 3];
            #pragma unroll
            for (int c = 0; c < 4; ++c) {
                dp[c] = P[c+2] - P[c];
                eq[c] = Q[c] + 2.f*Q[c+1] + Q[c+2];
            }
        }
        if (mI < 2) continue;
        const int o = mI - 2;   // out row: gy = ty0 + r0 + o (always in-domain)
        {
            const float* d0 = dP[(mI - 2) % 3];
            const float* d1 = dP[(mI - 1) % 3];
            const float* d2 = dP[mI % 3];
            const float* e0 = eQ[(mI - 2) % 3];
            const float* e2 = eQ[mI % 3];
            const float4 ur = *(const float4*)&s.su[r0 + o + 3][c0 + 4];
            float o0 = ur.x + (d0[0] + 2.f*d1[0] + d2[0]) + (e2[0] - e0[0]);
            float o1 = ur.y + (d0[1] + 2.f*d1[1] + d2[1]) + (e2[1] - e0[1]);
            float o2 = ur.z + (d0[2] + 2.f*d1[2] + d2[2]) + (e2[2] - e0[2]);
            float o3 = ur.w + (d0[3] + 2.f*d1[3] + d2[3]) + (e2[3] - e0[3]);
            *(float4*)(oc + obase + (long)o * W) = make_float4(o0, o1, o2, o3);
        }
    }
}

extern "C" void kernel_launch(void* const* d_in, const int* in_sizes, int n_in,
                              void* d_out, int out_size, void* d_ws, size_t ws_size,
                              hipStream_t stream) {
    const float* u = (const float*)d_in[0];
    float* out = (float*)d_out;

    const int H = 512, W = 512;
    const int channels = in_sizes[0] / (H * W);  // B*C = 48

    dim3 grid(W / TW, H / TH, channels);
    dim3 block(NT);
    gcdd_fused<<<grid, block, 0, stream>>>(u, out, H, W);
}

// Round 6
// 70.295 us; speedup vs baseline: 1.9443x; 1.9443x over previous
//
#include <hip/hip_runtime.h>
#include <math.h>

// GCDD fused v6: R3 structure + pre-reduced s1/s2 storage + pow2 mappings.
// out = u + div( phi(G)*ux, phi(G)*uy ); 3x3 Sobel cross-correlations with zero
// padding at EVERY conv stage (intermediates forced to 0 outside the domain).
//
// Stage 1: u tile -> LDS (su).
// Stage 3: per 4x4 task, rolling register pipeline u->ux,uy->P,Q, then store the
//   HORIZONTALLY PRE-REDUCED rows: s1[c]=P[c+1]-P[c-1], s2[c]=Q[c-1]+2Q[c]+Q[c+1].
//   s1/s2 are exactly tile-width -> 16 power-of-2 col groups (R3's mod-17 mapping
//   was the measured 2.1e7-cycle bank-conflict source).
// Stage 4: out[r] = u[r] + (s1[r]+2*s1[r+1]+s1[r+2]) + (s2[r+2]-s2[r])
//   (s row rs corresponds to P row rs-1; vertical Sobel weights absorbed).
//
// Tile 64x32, 256 threads. su[r][c]: gy=ty0+r-3 (r=0..37; 38,39 pad for the
// last stage-3 quad's masked rows), gx=tx0+c-4. s1/s2[rs][c]: P row rs-1,
// out col c (rs=0..33 used; 34,35 pad).
// NO launch_bounds min-waves (R5 lesson: capping below live state -> spills).

#define TW 64
#define TH 32
#define NT 256

struct Smem {
    float su[40][72];   // stride 72 (≡8 mod 32)
    float s1[36][68];   // stride 68 (≡4 mod 32)
    float s2[36][68];
};

__global__ __launch_bounds__(NT) void gcdd_fused(
    const float* __restrict__ u, float* __restrict__ out, int H, int W)
{
    __shared__ Smem s;
    const int tid = threadIdx.x;
    const int tx0 = blockIdx.x * TW;
    const int ty0 = blockIdx.y * TH;
    const long chan = blockIdx.z;
    const float* __restrict__ uc = u + chan * (long)H * W;
    float* __restrict__ oc = out + chan * (long)H * W;

    const bool inr = (tx0 >= 4) && (tx0 + 68 <= W) && (ty0 >= 3) && (ty0 + 35 <= H);

    // ---- Stage 1: u rows 0..37 (gy=ty0+r-3), 18 float4 col-groups ----
    for (int i = tid; i < 38 * 18; i += NT) {
        const int r = i / 18, g = i - r * 18;
        const int gy = ty0 + r - 3;
        const int gxb = tx0 + g * 4 - 4;
        float4 v;
        if (inr) {
            v = *(const float4*)(uc + (long)gy * W + gxb);
        } else {
            float e[4];
            #pragma unroll
            for (int k = 0; k < 4; ++k) {
                const int gx = gxb + k;
                const bool in = ((unsigned)gy < (unsigned)H) & ((unsigned)gx < (unsigned)W);
                e[k] = in ? uc[(long)gy * W + gx] : 0.f;
            }
            v = make_float4(e[0], e[1], e[2], e[3]);
        }
        *(float4*)&s.su[r][g * 4] = v;
    }
    __syncthreads();

    // ---- Stage 3: 144 tasks (16 col-groups x 9 row-quads), 4x4 s-rows each ----
    if (tid < 144) {
        const int g   = tid & 15;
        const int rq  = tid >> 4;        // 0..8
        const int c0  = g * 4;           // out-col base; s col c0..c0+3
        const int rs0 = rq * 4;          // s row base (s row rs -> P row rs-1)

        bool mx[8];                      // ux col validity: gx = tx0+c0-2+c
        #pragma unroll
        for (int c = 0; c < 8; ++c)
            mx[c] = (unsigned)(tx0 + c0 - 2 + c) < (unsigned)W;

        float uw[3][12], xw[3][8], yw[3][8];

        #pragma unroll
        for (int k = 0; k < 8; ++k) {
            {   // u row: su row rs0+k (gy = ty0 + rs0 + k - 3), cols c0..c0+11
                float* w = uw[k % 3];
                *(float4*)&w[0] = *(const float4*)&s.su[rs0 + k][c0];
                *(float4*)&w[4] = *(const float4*)&s.su[rs0 + k][c0 + 4];
                *(float4*)&w[8] = *(const float4*)&s.su[rs0 + k][c0 + 8];
            }
            if (k < 2) continue;
            const int e = k - 2;         // ux/uy row: gy = ty0 + rs0 + e - 2
            {
                const float* t = uw[(k - 2) % 3];
                const float* md = uw[(k - 1) % 3];
                const float* b = uw[k % 3];
                float* xr = xw[e % 3];
                float* yr = yw[e % 3];
                const bool iny = (unsigned)(ty0 + rs0 + e - 2) < (unsigned)H;
                #pragma unroll
                for (int c = 0; c < 8; ++c) {   // ux col: gx = tx0+c0-2+c
                    float A = t[c+1],  B = t[c+2],  C = t[c+3];
                    float D = md[c+1],              E = md[c+3];
                    float F = b[c+1],  Gg = b[c+2], Hh = b[c+3];
                    float x = (C - A) + 2.f*(E - D) + (Hh - F);       // SOBEL_X
                    float y = (F + 2.f*Gg + Hh) - (A + 2.f*B + C);    // SOBEL_Y
                    const bool in = iny & mx[c];
                    xr[c] = in ? x : 0.f;
                    yr[c] = in ? y : 0.f;
                }
            }
            if (e < 2) continue;
            const int m = e - 2;         // P row: gy = ty0 + rs0 - 1 + m; s row rs0+m
            {
                const float* xt = xw[m % 3];
                const float* xm = xw[(m + 1) % 3];
                const float* xb = xw[(m + 2) % 3];
                const float* yt = yw[m % 3];
                const float* ym = yw[(m + 1) % 3];
                const float* yb = yw[(m + 2) % 3];
                const bool iny = (unsigned)(ty0 + rs0 - 1 + m) < (unsigned)H;
                float P[6], Q[6];
                #pragma unroll
                for (int c = 0; c < 6; ++c) {   // P col: gx = tx0+c0-1+c, ux idx c..c+2
                    float xc = xm[c+1], yc = ym[c+1];
                    float uxx = (xt[c+2]-xt[c]) + 2.f*(xm[c+2]-xm[c]) + (xb[c+2]-xb[c]);
                    float uxy = (xb[c] + 2.f*xb[c+1] + xb[c+2])
                              - (xt[c] + 2.f*xt[c+1] + xt[c+2]);
                    float uyy = (yb[c] + 2.f*yb[c+1] + yb[c+2])
                              - (yt[c] + 2.f*yt[c+1] + yt[c+2]);
                    float den = 1.f + xc*xc + yc*yc;
                    float Gv = (uxx*uyy - uxy*uxy)
                             * __builtin_amdgcn_rcpf(den*den + 1e-6f);
                    float phi = __expf(-fabsf(Gv));
                    const bool in = iny & mx[c + 1];
                    P[c] = in ? phi * xc : 0.f;
                    Q[c] = in ? phi * yc : 0.f;
                }
                if (rs0 + m < 34) {
                    float4 v1, v2;
                    v1.x = P[2] - P[0];  v1.y = P[3] - P[1];
                    v1.z = P[4] - P[2];  v1.w = P[5] - P[3];
                    v2.x = Q[0] + 2.f*Q[1] + Q[2];
                    v2.y = Q[1] + 2.f*Q[2] + Q[3];
                    v2.z = Q[2] + 2.f*Q[3] + Q[4];
                    v2.w = Q[3] + 2.f*Q[4] + Q[5];
                    *(float4*)&s.s1[rs0 + m][c0] = v1;
                    *(float4*)&s.s2[rs0 + m][c0] = v2;
                }
            }
        }
    }
    __syncthreads();

    // ---- Stage 4: 256 tasks (16 col-groups x 16 row-pairs), 4x2 outputs each ----
    {
        const int g = tid & 15;
        const int p = tid >> 4;          // 0..15
        const int c4 = g * 4;
        const int r0 = 2 * p;            // out rows r0, r0+1; s rows r0..r0+3

        float a1[4][4], a2[4][4];
        #pragma unroll
        for (int j = 0; j < 4; ++j) {
            *(float4*)a1[j] = *(const float4*)&s.s1[r0 + j][c4];
            *(float4*)a2[j] = *(const float4*)&s.s2[r0 + j][c4];
        }
        #pragma unroll
        for (int m = 0; m < 2; ++m) {
            const int r = r0 + m;
            const float4 ur = *(const float4*)&s.su[r + 3][c4 + 4];
            const float urv[4] = {ur.x, ur.y, ur.z, ur.w};
            float o[4];
            #pragma unroll
            for (int c = 0; c < 4; ++c) {
                o[c] = urv[c]
                     + (a1[m][c] + 2.f*a1[m+1][c] + a1[m+2][c])
                     + (a2[m+2][c] - a2[m][c]);
            }
            *(float4*)(oc + (long)(ty0 + r) * W + (tx0 + c4)) =
                make_float4(o[0], o[1], o[2], o[3]);
        }
    }
}

extern "C" void kernel_launch(void* const* d_in, const int* in_sizes, int n_in,
                              void* d_out, int out_size, void* d_ws, size_t ws_size,
                              hipStream_t stream) {
    const float* u = (const float*)d_in[0];
    float* out = (float*)d_out;

    const int H = 512, W = 512;
    const int channels = in_sizes[0] / (H * W);  // B*C = 48

    dim3 grid(W / TW, H / TH, channels);
    dim3 block(NT);
    gcdd_fused<<<grid, block, 0, stream>>>(u, out, H, W);
}

// Round 7
// 48.327 us; speedup vs baseline: 2.8281x; 1.4546x over previous
//
#include <hip/hip_runtime.h>
#include <math.h>

// GCDD fused v7: zero-LDS register-pipeline sweep.
// out = u + div( phi(G)*ux, phi(G)*uy ); 3x3 Sobel cross-correlations with zero
// padding at EVERY conv stage (intermediates forced to 0 outside the domain).
//
// Each thread owns a 4-wide x HB-tall output strip and sweeps down rows with a
// depth-3 rolling register pipeline, loading u straight from global (3 float4
// per row; neighbor-lane overlap hits L1, so HBM fetch is only the band halo):
//   iter T: load u band-row T (abs gy=gy0+T-3) -> ux/uy row T-1 -> P,Q row T-2
//           (stored pre-reduced: dP=P[c+1]-P[c-1], eQ=Q[c-1]+2Q[c]+Q[c+1])
//           -> out row T-3 (abs gy=gy0+T-6).
// Slots: uw/ucen by u-row%3 (S0), xw/yw by ux-row%3 (S2), dP/eQ by P-row%3 (S1).
// No LDS, no barriers, no idle lanes, single masked code path (R4 lesson: no
// dual-inline; R5 lesson: no launch_bounds VGPR cap below live state).
//
// Block: 256 threads = 2 bands x 128 strips (full W=512). Grid y = H/(2*HB).

#define HB   16
#define NROW (HB + 6)   // 22 active pipeline iterations, loop padded to 24
#define NT   256

#define STEP(TT, S0, S1, S2) do {                                              \
    const int Tt = (TT);                                                       \
    /* residual u (row written at L(Tt-3), slot S0) BEFORE L overwrites it */  \
    float ur0 = ucen[S0][0], ur1 = ucen[S0][1],                                \
          ur2 = ucen[S0][2], ur3 = ucen[S0][3];                                \
    if (Tt < NROW) {                                                           \
        /* ---- L(Tt): u band-row Tt, abs gy = gy0+Tt-3 ---- */                \
        const int gy = gy0 + Tt - 3;                                           \
        float* w = uw[S0];                                                     \
        if ((unsigned)gy < (unsigned)H) {                                      \
            const float* row = uc + (long)gy * W;                              \
            const float4 va = *(const float4*)(row + ca);                      \
            const float4 vb = *(const float4*)(row + c0);                      \
            const float4 vc = *(const float4*)(row + cc);                      \
            w[0] = inb0  ? va.x : 0.f;  w[1]  = inb1  ? va.y : 0.f;            \
            w[2] = inb2  ? va.z : 0.f;  w[3]  = inb3  ? va.w : 0.f;            \
            w[4] = vb.x;                w[5]  = vb.y;                          \
            w[6] = vb.z;                w[7]  = vb.w;                          \
            w[8] = inb8  ? vc.x : 0.f;  w[9]  = inb9  ? vc.y : 0.f;            \
            w[10] = inb10 ? vc.z : 0.f; w[11] = inb11 ? vc.w : 0.f;            \
        } else {                                                               \
            _Pragma("unroll") for (int i = 0; i < 12; ++i) w[i] = 0.f;         \
        }                                                                      \
        ucen[S0][0] = w[4]; ucen[S0][1] = w[5];                                \
        ucen[S0][2] = w[6]; ucen[S0][3] = w[7];                                \
    }                                                                          \
    if (Tt >= 2 && Tt < NROW) {                                                \
        /* ---- UX(Tt): ux/uy band-row Tt-1, abs gy = gy0+Tt-4 ---- */         \
        float* xr = xw[S2]; float* yr = yw[S2];                                \
        const int gy = gy0 + Tt - 4;                                           \
        if ((unsigned)gy < (unsigned)H) {                                      \
            const float* a = uw[S1];   /* row Tt-2 */                          \
            const float* m = uw[S2];   /* row Tt-1 */                          \
            const float* b = uw[S0];   /* row Tt   */                          \
            _Pragma("unroll") for (int c = 0; c < 8; ++c) {                    \
                const float A = a[c+1], B = a[c+2], C = b_ = a[c+3];           \
                const float D = m[c+1],             E = m[c+3];                \
                const float F = b[c+1], Gg = b[c+2], Hh = b[c+3];              \
                float x = (C - A) + 2.f*(E - D) + (Hh - F);                    \
                float y = (F + 2.f*Gg + Hh) - (A + 2.f*B + C);                 \
                xr[c] = mU[c+2] ? x : 0.f;                                     \
                yr[c] = mU[c+2] ? y : 0.f;                                     \
            }                                                                  \
        } else {                                                               \
            _Pragma("unroll") for (int c = 0; c < 8; ++c) { xr[c]=0.f; yr[c]=0.f; } \
        }                                                                      \
    }                                                                          \
    if (Tt >= 4 && Tt < NROW) {                                                \
        /* ---- PQ(Tt): P band-row Tt-2, abs gy = gy0+Tt-5 ---- */             \
        float* dp = dP[S1]; float* eq = eQ[S1];                                \
        const int gy = gy0 + Tt - 5;                                           \
        if ((unsigned)gy < (unsigned)H) {                                      \
            const float* xt = xw[S0];  /* ux row Tt-3 */                       \
            const float* xm = xw[S1];  /* ux row Tt-2 */                       \
            const float* xb = xw[S2];  /* ux row Tt-1 */                       \
            const float* yt = yw[S0];                                          \
            const float* ym = yw[S1];                                          \
            const float* yb = yw[S2];                                          \
            float P[6], Q[6];                                                  \
            _Pragma("unroll") for (int c = 0; c < 6; ++c) {                    \
                const float xc = xm[c+1], yc = ym[c+1];                        \
                const float uxx = (xt[c+2]-xt[c]) + 2.f*(xm[c+2]-xm[c])        \
                                + (xb[c+2]-xb[c]);                             \
                const float uxy = (xb[c] + 2.f*xb[c+1] + xb[c+2])              \
                                - (xt[c] + 2.f*xt[c+1] + xt[c+2]);             \
                const float uyy = (yb[c] + 2.f*yb[c+1] + yb[c+2])              \
                                - (yt[c] + 2.f*yt[c+1] + yt[c+2]);             \
                const float den = 1.f + xc*xc + yc*yc;                         \
                const float Gv = (uxx*uyy - uxy*uxy)                           \
                               * __builtin_amdgcn_rcpf(den*den + 1e-6f);       \
                const float phi = __expf(-fabsf(Gv));                          \
                P[c] = mU[c+3] ? phi * xc : 0.f;                               \
                Q[c] = mU[c+3] ? phi * yc : 0.f;                               \
            }                                                                  \
            dp[0] = P[2]-P[0]; dp[1] = P[3]-P[1];                              \
            dp[2] = P[4]-P[2]; dp[3] = P[5]-P[3];                              \
            eq[0] = Q[0]+2.f*Q[1]+Q[2]; eq[1] = Q[1]+2.f*Q[2]+Q[3];            \
            eq[2] = Q[2]+2.f*Q[3]+Q[4]; eq[3] = Q[3]+2.f*Q[4]+Q[5];            \
        } else {                                                               \
            _Pragma("unroll") for (int c = 0; c < 4; ++c) { dp[c]=0.f; eq[c]=0.f; } \
        }                                                                      \
    }                                                                          \
    if (Tt >= 6 && Tt < NROW) {                                                \
        /* ---- OUT(Tt): out row abs gy = gy0+Tt-6 (always in-domain) ---- */  \
        /* P rows: gy-1 -> slot S2 (w=1), gy -> S0 (w=2), gy+1 -> S1 (w=1) */  \
        float o0 = ur0 + (dP[S2][0] + 2.f*dP[S0][0] + dP[S1][0])               \
                       + (eQ[S1][0] - eQ[S2][0]);                              \
        float o1 = ur1 + (dP[S2][1] + 2.f*dP[S0][1] + dP[S1][1])               \
                       + (eQ[S1][1] - eQ[S2][1]);                              \
        float o2 = ur2 + (dP[S2][2] + 2.f*dP[S0][2] + dP[S1][2])               \
                       + (eQ[S1][2] - eQ[S2][2]);                              \
        float o3 = ur3 + (dP[S2][3] + 2.f*dP[S0][3] + dP[S1][3])               \
                       + (eQ[S1][3] - eQ[S2][3]);                              \
        *(float4*)(oc + (long)(gy0 + Tt - 6) * W + c0) =                       \
            make_float4(o0, o1, o2, o3);                                       \
    }                                                                          \
} while (0)

__global__ __launch_bounds__(NT) void gcdd_sweep(
    const float* __restrict__ u, float* __restrict__ out, int H, int W)
{
    const int tid   = threadIdx.x;
    const int strip = tid & 127;          // 128 strips x 4 cols = W = 512
    const int band  = tid >> 7;           // 2 bands per block (wave-uniform)
    const int c0    = strip * 4;
    const int gy0   = (blockIdx.y * 2 + band) * HB;
    const long chan = blockIdx.z;
    const float* __restrict__ uc = u + chan * (long)H * W;
    float* __restrict__ oc = out + chan * (long)H * W;

    // Clamped load-base cols (keeps addresses in-bounds; clamped-in values are
    // masked to zero below, implementing the zero-padding of the first conv).
    const int ca = (c0 - 4 < 0) ? 0 : (c0 - 4);
    const int cc = (c0 + 4 > W - 4) ? (W - 4) : (c0 + 4);

    // uw[i] holds u col c0-4+i; validity masks (only edge strips have false).
    bool mU[12];
    #pragma unroll
    for (int i = 0; i < 12; ++i)
        mU[i] = (unsigned)(c0 - 4 + i) < (unsigned)W;
    const bool inb0 = mU[0], inb1 = mU[1], inb2 = mU[2], inb3 = mU[3];
    const bool inb8 = mU[8], inb9 = mU[9], inb10 = mU[10], inb11 = mU[11];

    float uw[3][12];
    float ucen[3][4] = {};
    float xw[3][8], yw[3][8];
    float dP[3][4], eQ[3][4];
    float b_;  // scratch sink for macro (avoids unused-var warnings)
    (void)b_;

    // 24 iterations (22 active), 3-unrolled so all slot indices are literal.
    for (int t = 0; t < NROW + 2; t += 3) {
        STEP(t + 0, 0, 1, 2);
        STEP(t + 1, 1, 2, 0);
        STEP(t + 2, 2, 0, 1);
    }
}

extern "C" void kernel_launch(void* const* d_in, const int* in_sizes, int n_in,
                              void* d_out, int out_size, void* d_ws, size_t ws_size,
                              hipStream_t stream) {
    const float* u = (const float*)d_in[0];
    float* out = (float*)d_out;

    const int H = 512, W = 512;
    const int channels = in_sizes[0] / (H * W);  // B*C = 48

    dim3 grid(1, H / (2 * HB), channels);        // 1 x 16 x 48 = 768 blocks
    dim3 block(NT);
    gcdd_sweep<<<grid, block, 0, stream>>>(u, out, H, W);
}